// Round 5
// baseline (137.488 us; speedup 1.0000x reference)
//
#include <hip/hip_runtime.h>
#include <stdint.h>

// Problem constants (fixed shapes from the reference)
#define HEADS 8
#define DIM   512
#define HD    64
#define NE    16      // entities per sentence
#define NS    64      // sentences
#define NB    64      // batch

typedef short bf16x8 __attribute__((ext_vector_type(8)));
typedef float f32x4  __attribute__((ext_vector_type(4)));

__device__ __forceinline__ unsigned short f2bf(float f) {
    union { float f; uint32_t u; } v; v.f = f;
    uint32_t u = v.u;
    u += 0x7fffu + ((u >> 16) & 1u);   // RNE
    return (unsigned short)(u >> 16);
}

// pack 8 fp32 -> bf16x8 via HW RNE converts (no builtin on gfx950 -> asm)
__device__ __forceinline__ bf16x8 cvt8(f32x4 lo, f32x4 hi) {
    union { uint32_t u[4]; bf16x8 v; } r;
    asm("v_cvt_pk_bf16_f32 %0, %1, %2" : "=v"(r.u[0]) : "v"(lo.x), "v"(lo.y));
    asm("v_cvt_pk_bf16_f32 %0, %1, %2" : "=v"(r.u[1]) : "v"(lo.z), "v"(lo.w));
    asm("v_cvt_pk_bf16_f32 %0, %1, %2" : "=v"(r.u[2]) : "v"(hi.x), "v"(hi.y));
    asm("v_cvt_pk_bf16_f32 %0, %1, %2" : "=v"(r.u[3]) : "v"(hi.z), "v"(hi.w));
    return r.v;
}

// ---------------------------------------------------------------------------
// K0: fused prep (528 blocks).
//   blocks [0,16):    u_f[h][c] = sum_j (wq[h64+j]·query + bq[h64+j]) * wk[h64+j][c]
//                     (h = bid>>1, c-half = bid&1; qvec computed in-block)
//   blocks [16,272):  wv -> bf16
//   blocks [272,528): wo -> bf16
// q_h · bk_h is softmax-invariant -> bk unused.
// ---------------------------------------------------------------------------
__global__ __launch_bounds__(256) void k_prep(
    const float* __restrict__ qp, const float* __restrict__ wq,
    const float* __restrict__ bq, const float* __restrict__ wk,
    const float* __restrict__ wv, const float* __restrict__ wo,
    float* __restrict__ u_f,
    unsigned short* __restrict__ wv_bf, unsigned short* __restrict__ wo_bf)
{
    const int bid = blockIdx.x;
    const int t = threadIdx.x;
    if (bid < 16) {
        const int h = bid >> 1, ch = bid & 1;
        __shared__ float qs[HD];
        {   // qvec for head h: thread (j = t>>2, q = t&3) sums 128 elems
            const int j = t >> 2, q = t & 3;
            const float* w = wq + (size_t)(h * HD + j) * DIM + q * 128;
            const float* qq = qp + q * 128;
            float a = 0.f;
            #pragma unroll 8
            for (int i = 0; i < 128; i++) a += w[i] * qq[i];
            a += __shfl_xor(a, 1);
            a += __shfl_xor(a, 2);
            if (q == 0) qs[j] = a + bq[h * HD + j];
        }
        __syncthreads();
        const int c = ch * 256 + t;
        const float* w = wk + (size_t)(h * HD) * DIM + c;
        float acc = 0.f;
        #pragma unroll 8
        for (int j = 0; j < HD; j++) acc += qs[j] * w[(size_t)j * DIM];
        u_f[h * DIM + c] = acc;
        return;
    }
    const bool is_v = bid < 272;
    const float* src = is_v ? wv : wo;
    unsigned short* dst = is_v ? wv_bf : wo_bf;
    const int li = ((is_v ? bid - 16 : bid - 272) * 1024 + t * 4);
    const float4 v = *(const float4*)(src + li);
    ushort4 hv;
    hv.x = f2bf(v.x); hv.y = f2bf(v.y); hv.z = f2bf(v.z); hv.w = f2bf(v.w);
    *(ushort4*)(dst + li) = hv;
}

// ---------------------------------------------------------------------------
// K1: single-pass streaming attention. One WAVE per (s,b); 1024 blocks x 4 waves.
// No LDS, no barriers, no MFMA, zero duplicated loads.
//   lane owns d0 = 8*lane (8 contiguous d). Per entity row (16 total):
//     2x dwordx4 load (wave reads the full 2KB row, perfectly coalesced)
//     score partials for 8 heads (64 FMA) -> 6-step shuffle reduce
//     online softmax WITHOUT max-sub (scores ~N(0,0.12), clamp +-30 for safety;
//       softmax is shift-invariant so result is exact)
//     accumulate acc[h] += p[h] * row  (row still in regs -> single HBM pass)
//   Final: acc * (1/sum) -> bf16 store (coalesced 1KB per head).
// 2-row register prefetch keeps ~4KB/wave of HBM traffic in flight.
// ---------------------------------------------------------------------------
__global__ __launch_bounds__(256) void k_attn(
    const float* __restrict__ ents, const float* __restrict__ u_f,
    unsigned short* __restrict__ weighted)
{
    const int t = threadIdx.x;
    const int w = t >> 6, lane = t & 63;
    // XCD-aware bijective swizzle (1024 = 8*128): s-chunks per XCD for L2 reuse
    const int bid = ((int)blockIdx.x & 7) * 128 + ((int)blockIdx.x >> 3);
    const int s = bid >> 4;
    const int b = ((bid & 15) << 2) | w;
    const int d0 = lane << 3;

    // u fragments: 8 heads x 8 d = 64 f32
    f32x4 u0[HEADS], u1[HEADS];
    #pragma unroll
    for (int h = 0; h < HEADS; h++) {
        u0[h] = *(const f32x4*)(u_f + h * DIM + d0);
        u1[h] = *(const f32x4*)(u_f + h * DIM + d0 + 4);
    }

    const float* base = ents + ((size_t)(s * NE) * NB + b) * DIM + d0;
    const int ROWSTRIDE = NB * DIM;   // 32768 floats between entity rows

    f32x4 acc0[HEADS], acc1[HEADS];
    float sum[HEADS];
    #pragma unroll
    for (int h = 0; h < HEADS; h++) {
        acc0[h] = (f32x4){0.f, 0.f, 0.f, 0.f};
        acc1[h] = (f32x4){0.f, 0.f, 0.f, 0.f};
        sum[h] = 0.f;
    }

    // 2-deep register prefetch
    f32x4 cur0 = *(const f32x4*)(base);
    f32x4 cur1 = *(const f32x4*)(base + 4);
    f32x4 nxt0 = *(const f32x4*)(base + ROWSTRIDE);
    f32x4 nxt1 = *(const f32x4*)(base + ROWSTRIDE + 4);

    #pragma unroll
    for (int e = 0; e < NE; e++) {
        const f32x4 r0 = cur0, r1 = cur1;
        cur0 = nxt0; cur1 = nxt1;
        if (e < NE - 2) {
            nxt0 = *(const f32x4*)(base + (size_t)(e + 2) * ROWSTRIDE);
            nxt1 = *(const f32x4*)(base + (size_t)(e + 2) * ROWSTRIDE + 4);
        }
        // per-head partial dots over this lane's 8 d
        float pd[HEADS];
        #pragma unroll
        for (int h = 0; h < HEADS; h++) {
            pd[h] = r0.x * u0[h].x + r0.y * u0[h].y + r0.z * u0[h].z + r0.w * u0[h].w
                  + r1.x * u1[h].x + r1.y * u1[h].y + r1.z * u1[h].z + r1.w * u1[h].w;
        }
        // full-wave reduce (64 lanes) per head
        #pragma unroll
        for (int msk = 1; msk <= 32; msk <<= 1)
            #pragma unroll
            for (int h = 0; h < HEADS; h++) pd[h] += __shfl_xor(pd[h], msk);
        // online (shift-free) softmax accumulate; row still live in registers
        #pragma unroll
        for (int h = 0; h < HEADS; h++) {
            const float sc = fminf(fmaxf(pd[h] * 0.125f, -30.f), 30.f);
            const float p = __expf(sc);
            sum[h] += p;
            acc0[h] += p * r0;
            acc1[h] += p * r1;
        }
    }

    unsigned short* wrow = weighted + ((size_t)(s * NB + b) << 12) + d0;
    #pragma unroll
    for (int h = 0; h < HEADS; h++) {
        const float inv = 1.f / sum[h];
        const bf16x8 ov = cvt8(acc0[h] * inv, acc1[h] * inv);
        *(bf16x8*)(wrow + h * DIM) = ov;
    }
}

// ---------------------------------------------------------------------------
// K2/K3: C[M=4096, 64 cols per y] = A(bf16) @ B^T(bf16) + bias
// BM=64, BN=64, BK=64; 4 waves, each wave a 16-row strip x 64 cols.
//   K2: A=weighted (lda 4096, col off 512*y=head), B=wv_bf rows 64y.. -> ctx bf16
//   K3: A=ctx      (lda 512),                      B=wo_bf rows 64y.. -> out f32
// ---------------------------------------------------------------------------
template <typename CT>
__global__ __launch_bounds__(256) void k_gemm(
    const unsigned short* __restrict__ A, int lda, int aOffY,
    const unsigned short* __restrict__ B, int ldb, int bOffY,
    const float* __restrict__ bias, CT* __restrict__ C, int ldc, int cOffY, int K)
{
    __shared__ unsigned short a_s[64][72];
    __shared__ unsigned short b_s[64][72];
    const int t = threadIdx.x;
    const int m0 = blockIdx.x * 64;
    const int y  = blockIdx.y;
    const int w = t >> 6, l = t & 63;
    const int m = l & 15, g = l >> 4;
    const int lr = t >> 2, lk = (t & 3) * 16;

    const unsigned short* Ap = A + (size_t)(m0 + lr) * lda + (size_t)aOffY * y;
    const unsigned short* Bp = B + (size_t)(bOffY * y + lr) * ldb;

    f32x4 acc[4];
    #pragma unroll
    for (int i = 0; i < 4; i++) acc[i] = (f32x4){0.f, 0.f, 0.f, 0.f};

    for (int k0 = 0; k0 < K; k0 += 64) {
        const ushort4 av0 = *(const ushort4*)(Ap + k0 + lk);
        const ushort4 av1 = *(const ushort4*)(Ap + k0 + lk + 4);
        const ushort4 av2 = *(const ushort4*)(Ap + k0 + lk + 8);
        const ushort4 av3 = *(const ushort4*)(Ap + k0 + lk + 12);
        const ushort4 bv0 = *(const ushort4*)(Bp + k0 + lk);
        const ushort4 bv1 = *(const ushort4*)(Bp + k0 + lk + 4);
        const ushort4 bv2 = *(const ushort4*)(Bp + k0 + lk + 8);
        const ushort4 bv3 = *(const ushort4*)(Bp + k0 + lk + 12);
        *(ushort4*)&a_s[lr][lk]      = av0;
        *(ushort4*)&a_s[lr][lk + 4]  = av1;
        *(ushort4*)&a_s[lr][lk + 8]  = av2;
        *(ushort4*)&a_s[lr][lk + 12] = av3;
        *(ushort4*)&b_s[lr][lk]      = bv0;
        *(ushort4*)&b_s[lr][lk + 4]  = bv1;
        *(ushort4*)&b_s[lr][lk + 8]  = bv2;
        *(ushort4*)&b_s[lr][lk + 12] = bv3;
        __syncthreads();
        #pragma unroll
        for (int kk = 0; kk < 64; kk += 32) {
            const int kp = kk + g * 8;
            const bf16x8 af = *(const bf16x8*)&a_s[w * 16 + m][kp];
            const bf16x8 b0 = *(const bf16x8*)&b_s[ 0 + m][kp];
            const bf16x8 b1 = *(const bf16x8*)&b_s[16 + m][kp];
            const bf16x8 b2 = *(const bf16x8*)&b_s[32 + m][kp];
            const bf16x8 b3 = *(const bf16x8*)&b_s[48 + m][kp];
            acc[0] = __builtin_amdgcn_mfma_f32_16x16x32_bf16(af, b0, acc[0], 0, 0, 0);
            acc[1] = __builtin_amdgcn_mfma_f32_16x16x32_bf16(af, b1, acc[1], 0, 0, 0);
            acc[2] = __builtin_amdgcn_mfma_f32_16x16x32_bf16(af, b2, acc[2], 0, 0, 0);
            acc[3] = __builtin_amdgcn_mfma_f32_16x16x32_bf16(af, b3, acc[3], 0, 0, 0);
        }
        __syncthreads();
    }

    const int colbase = cOffY * y;
    #pragma unroll
    for (int nt = 0; nt < 4; nt++) {
        const int col = colbase + nt * 16 + m;
        const float bs = bias[col];
        #pragma unroll
        for (int j = 0; j < 4; j++) {
            const int row = m0 + w * 16 + g * 4 + j;
            const float val = acc[nt][j] + bs;
            if (sizeof(CT) == 2) {
                ((unsigned short*)C)[(size_t)row * ldc + col] = f2bf(val);
            } else {
                ((float*)C)[(size_t)row * ldc + col] = val;
            }
        }
    }
}

// ---------------------------------------------------------------------------
extern "C" void kernel_launch(void* const* d_in, const int* in_sizes, int n_in,
                              void* d_out, int out_size, void* d_ws, size_t ws_size,
                              hipStream_t stream)
{
    const float* ents = (const float*)d_in[0];
    const float* qp   = (const float*)d_in[1];
    const float* wq   = (const float*)d_in[2];
    const float* wk   = (const float*)d_in[3];
    const float* wv   = (const float*)d_in[4];
    const float* wo   = (const float*)d_in[5];
    const float* bq   = (const float*)d_in[6];
    // d_in[7] = bk: per-head softmax-invariant constant -> algebraically unused
    const float* bv   = (const float*)d_in[8];
    const float* bo   = (const float*)d_in[9];

    // workspace layout (~40 MB)
    char* ws = (char*)d_ws;
    float*          u_f      = (float*)ws;                                 // 16 KB [8][512] fp32
    unsigned short* wv_bf    = (unsigned short*)(ws + 65536);              // 512 KB
    unsigned short* wo_bf    = (unsigned short*)(ws + 65536 + 524288);     // 512 KB
    unsigned short* weighted = (unsigned short*)(ws + 2097152);            // 32 MB [4096][4096]
    unsigned short* ctx      = (unsigned short*)(ws + 2097152 + 33554432); // 4 MB [4096][512]

    k_prep <<<528, 256, 0, stream>>>(qp, wq, bq, wk, wv, wo, u_f, wv_bf, wo_bf);
    k_attn <<<1024, 256, 0, stream>>>(ents, u_f, weighted);
    k_gemm<unsigned short><<<dim3(64, 8), 256, 0, stream>>>(
        weighted, HEADS * DIM, DIM, wv_bf, DIM, HD, bv, ctx, DIM, HD, DIM);
    k_gemm<float><<<dim3(64, 8), 256, 0, stream>>>(
        ctx, DIM, 0, wo_bf, DIM, HD, bo, (float*)d_out, DIM, HD, DIM);
}

// Round 6
// 90.898 us; speedup vs baseline: 1.5125x; 1.5125x over previous
//
#include <hip/hip_runtime.h>
#include <stdint.h>

// Problem constants (fixed shapes from the reference)
#define HEADS 8
#define DIM   512
#define HD    64
#define NE    16      // entities per sentence
#define NS    64      // sentences
#define NB    64      // batch

typedef short bf16x8 __attribute__((ext_vector_type(8)));
typedef float f32x4  __attribute__((ext_vector_type(4)));

__device__ __forceinline__ unsigned short f2bf(float f) {
    union { float f; uint32_t u; } v; v.f = f;
    uint32_t u = v.u;
    u += 0x7fffu + ((u >> 16) & 1u);   // RNE
    return (unsigned short)(u >> 16);
}

// pack 8 fp32 -> bf16x8 via HW RNE converts (no builtin on gfx950 -> asm)
__device__ __forceinline__ bf16x8 cvt8(f32x4 lo, f32x4 hi) {
    union { uint32_t u[4]; bf16x8 v; } r;
    asm("v_cvt_pk_bf16_f32 %0, %1, %2" : "=v"(r.u[0]) : "v"(lo.x), "v"(lo.y));
    asm("v_cvt_pk_bf16_f32 %0, %1, %2" : "=v"(r.u[1]) : "v"(lo.z), "v"(lo.w));
    asm("v_cvt_pk_bf16_f32 %0, %1, %2" : "=v"(r.u[2]) : "v"(hi.x), "v"(hi.y));
    asm("v_cvt_pk_bf16_f32 %0, %1, %2" : "=v"(r.u[3]) : "v"(hi.z), "v"(hi.w));
    return r.v;
}

// ---------------------------------------------------------------------------
// K0: fused prep (528 blocks).
//   blocks [0,16):    u_bf[h][c] = bf16( sum_j qvec_h[j] * wk[h*64+j][c] ),
//                     qvec_h computed in-block; rows 8..15 zeroed.
//   blocks [16,272):  wv -> bf16
//   blocks [272,528): wo -> bf16
// q_h · bk_h is softmax-invariant -> bk unused.
// ---------------------------------------------------------------------------
__global__ __launch_bounds__(256) void k_prep(
    const float* __restrict__ qp, const float* __restrict__ wq,
    const float* __restrict__ bq, const float* __restrict__ wk,
    const float* __restrict__ wv, const float* __restrict__ wo,
    unsigned short* __restrict__ u_bf,
    unsigned short* __restrict__ wv_bf, unsigned short* __restrict__ wo_bf)
{
    const int bid = blockIdx.x;
    const int t = threadIdx.x;
    if (bid < 16) {
        const int h = bid >> 1, ch = bid & 1;
        __shared__ float qs[HD];
        {   // qvec for head h: thread (j = t>>2, q = t&3) sums 128 elems
            const int j = t >> 2, q = t & 3;
            const float* w = wq + (size_t)(h * HD + j) * DIM + q * 128;
            const float* qq = qp + q * 128;
            float a = 0.f;
            #pragma unroll 8
            for (int i = 0; i < 128; i++) a += w[i] * qq[i];
            a += __shfl_xor(a, 1);
            a += __shfl_xor(a, 2);
            if (q == 0) qs[j] = a + bq[h * HD + j];
        }
        __syncthreads();
        const int c = ch * 256 + t;
        const float* w = wk + (size_t)(h * HD) * DIM + c;
        float acc = 0.f;
        #pragma unroll 8
        for (int j = 0; j < HD; j++) acc += qs[j] * w[(size_t)j * DIM];
        u_bf[h * DIM + c] = f2bf(acc);
        u_bf[(h + 8) * DIM + c] = 0;           // zero pad rows for MFMA N=16
        return;
    }
    const bool is_v = bid < 272;
    const float* src = is_v ? wv : wo;
    unsigned short* dst = is_v ? wv_bf : wo_bf;
    const int li = ((is_v ? bid - 16 : bid - 272) * 1024 + t * 4);
    const float4 v = *(const float4*)(src + li);
    ushort4 hv;
    hv.x = f2bf(v.x); hv.y = f2bf(v.y); hv.z = f2bf(v.z); hv.w = f2bf(v.w);
    *(ushort4*)(dst + li) = hv;
}

// ---------------------------------------------------------------------------
// K1: scores[s][b][h][e] = 0.125 * ent[se][b][:] . u[h][:]
// Skinny MFMA stream: block = one se (reads contiguous 128KB), 4 waves x 16 b.
// No LDS, no barriers, no cross-lane ops. A-fragments straight from global
// (fp32 -> bf16 in-reg); 16 fully-unrolled independent k-steps for MLP.
// ---------------------------------------------------------------------------
__global__ __launch_bounds__(256) void k_score(
    const float* __restrict__ ents, const unsigned short* __restrict__ u_bf,
    float* __restrict__ scores)
{
    const int t = threadIdx.x;
    const int w = t >> 6, lane = t & 63;
    const int m = lane & 15, g = lane >> 4;
    const int se = blockIdx.x;             // 0..1023
    const int s = se >> 4, e = se & 15;
    const int b0 = w * 16;

    const float* arow = ents + ((size_t)se * NB + b0 + m) * DIM + g * 8;
    const unsigned short* urow = u_bf + m * DIM + g * 8;   // B col m = head m (L2-hot)

    f32x4 acc = {0.f, 0.f, 0.f, 0.f};
    #pragma unroll
    for (int ks = 0; ks < 16; ks++) {
        const float4 f0 = *(const float4*)(arow + ks * 32);
        const float4 f1 = *(const float4*)(arow + ks * 32 + 4);
        const bf16x8 af = cvt8((f32x4){f0.x, f0.y, f0.z, f0.w},
                               (f32x4){f1.x, f1.y, f1.z, f1.w});
        const bf16x8 bf = *(const bf16x8*)(urow + ks * 32);
        acc = __builtin_amdgcn_mfma_f32_16x16x32_bf16(af, bf, acc, 0, 0, 0);
    }
    // D layout: col = lane&15 = head, row(within 16 b) = 4g+j
    if (m < HEADS) {
        #pragma unroll
        for (int j = 0; j < 4; j++) {
            const int b = b0 + 4 * g + j;
            scores[(((size_t)s * NB + b) * HEADS + m) * NE + e] = acc[j] * 0.125f;
        }
    }
}

// ---------------------------------------------------------------------------
// K2: softmax over e per (s,b,h); writes normalized p transposed to [sb][e][h].
// 32768 independent threads; 16 contiguous fp32 in, 16 strided 4B out.
// ---------------------------------------------------------------------------
__global__ __launch_bounds__(256) void k_softmax(
    const float* __restrict__ scores, float* __restrict__ p_t)
{
    const int idx = blockIdx.x * 256 + threadIdx.x;   // (sb)*8 + h
    const float* src = scores + (size_t)idx * NE;
    float v[16];
    #pragma unroll
    for (int i = 0; i < 4; i++) {
        const float4 x = *(const float4*)(src + i * 4);
        v[i*4+0] = x.x; v[i*4+1] = x.y; v[i*4+2] = x.z; v[i*4+3] = x.w;
    }
    float mx = v[0];
    #pragma unroll
    for (int i = 1; i < 16; i++) mx = fmaxf(mx, v[i]);
    float p[16], sum = 0.f;
    #pragma unroll
    for (int i = 0; i < 16; i++) { p[i] = __expf(v[i] - mx); sum += p[i]; }
    const float inv = 1.f / sum;
    float* dst = p_t + (size_t)(idx >> 3) * 128 + (idx & 7);
    #pragma unroll
    for (int i = 0; i < 16; i++) dst[i * 8] = p[i] * inv;
}

// ---------------------------------------------------------------------------
// K3: weighted[sb][h*512+d] = sum_e p_t[sb][e][h] * ent[s*16+e][b][d]
// Wave = one (s,b); lane owns d0 = 8*lane. Per e: 2 coalesced row-loads +
// 2 broadcast p-loads + 64 FMA. Zero shuffles/barriers/LDS; 16 unrolled
// independent iterations -> full MLP. Second entities pass ~= half L3 hits.
// ---------------------------------------------------------------------------
__global__ __launch_bounds__(256) void k_weighted(
    const float* __restrict__ ents, const float* __restrict__ p_t,
    unsigned short* __restrict__ weighted)
{
    const int t = threadIdx.x;
    const int w = t >> 6, lane = t & 63;
    const int sb = blockIdx.x * 4 + w;
    const int s = sb >> 6, b = sb & 63;
    const int d0 = lane << 3;

    const float* erow = ents + ((size_t)(s * NE) * NB + b) * DIM + d0;
    const float* prow = p_t + (size_t)sb * 128;
    const int ROWSTRIDE = NB * DIM;   // 32768 floats between entity rows

    f32x4 acc0[HEADS], acc1[HEADS];
    #pragma unroll
    for (int h = 0; h < HEADS; h++) { acc0[h] = (f32x4){0,0,0,0}; acc1[h] = (f32x4){0,0,0,0}; }

    #pragma unroll
    for (int e = 0; e < NE; e++) {
        const f32x4 r0 = *(const f32x4*)(erow + (size_t)e * ROWSTRIDE);
        const f32x4 r1 = *(const f32x4*)(erow + (size_t)e * ROWSTRIDE + 4);
        const f32x4 p0 = *(const f32x4*)(prow + e * 8);       // h 0..3 (broadcast)
        const f32x4 p1 = *(const f32x4*)(prow + e * 8 + 4);   // h 4..7
        acc0[0] += p0.x * r0; acc1[0] += p0.x * r1;
        acc0[1] += p0.y * r0; acc1[1] += p0.y * r1;
        acc0[2] += p0.z * r0; acc1[2] += p0.z * r1;
        acc0[3] += p0.w * r0; acc1[3] += p0.w * r1;
        acc0[4] += p1.x * r0; acc1[4] += p1.x * r1;
        acc0[5] += p1.y * r0; acc1[5] += p1.y * r1;
        acc0[6] += p1.z * r0; acc1[6] += p1.z * r1;
        acc0[7] += p1.w * r0; acc1[7] += p1.w * r1;
    }
    unsigned short* wrow = weighted + ((size_t)sb << 12) + d0;
    #pragma unroll
    for (int h = 0; h < HEADS; h++) {
        const bf16x8 ov = cvt8(acc0[h], acc1[h]);
        *(bf16x8*)(wrow + h * DIM) = ov;
    }
}

// ---------------------------------------------------------------------------
// K4/K5: C[M=4096, 64 cols per y] = A(bf16) @ B^T(bf16) + bias
// BM=64, BN=64, BK=64; 4 waves, each wave a 16-row strip x 64 cols.
//   K4: A=weighted (lda 4096, col off 512*y=head), B=wv_bf rows 64y.. -> ctx bf16
//   K5: A=ctx      (lda 512),                      B=wo_bf rows 64y.. -> out f32
// ---------------------------------------------------------------------------
template <typename CT>
__global__ __launch_bounds__(256) void k_gemm(
    const unsigned short* __restrict__ A, int lda, int aOffY,
    const unsigned short* __restrict__ B, int ldb, int bOffY,
    const float* __restrict__ bias, CT* __restrict__ C, int ldc, int cOffY, int K)
{
    __shared__ unsigned short a_s[64][72];
    __shared__ unsigned short b_s[64][72];
    const int t = threadIdx.x;
    const int m0 = blockIdx.x * 64;
    const int y  = blockIdx.y;
    const int w = t >> 6, l = t & 63;
    const int m = l & 15, g = l >> 4;
    const int lr = t >> 2, lk = (t & 3) * 16;

    const unsigned short* Ap = A + (size_t)(m0 + lr) * lda + (size_t)aOffY * y;
    const unsigned short* Bp = B + (size_t)(bOffY * y + lr) * ldb;

    f32x4 acc[4];
    #pragma unroll
    for (int i = 0; i < 4; i++) acc[i] = (f32x4){0.f, 0.f, 0.f, 0.f};

    for (int k0 = 0; k0 < K; k0 += 64) {
        const ushort4 av0 = *(const ushort4*)(Ap + k0 + lk);
        const ushort4 av1 = *(const ushort4*)(Ap + k0 + lk + 4);
        const ushort4 av2 = *(const ushort4*)(Ap + k0 + lk + 8);
        const ushort4 av3 = *(const ushort4*)(Ap + k0 + lk + 12);
        const ushort4 bv0 = *(const ushort4*)(Bp + k0 + lk);
        const ushort4 bv1 = *(const ushort4*)(Bp + k0 + lk + 4);
        const ushort4 bv2 = *(const ushort4*)(Bp + k0 + lk + 8);
        const ushort4 bv3 = *(const ushort4*)(Bp + k0 + lk + 12);
        *(ushort4*)&a_s[lr][lk]      = av0;
        *(ushort4*)&a_s[lr][lk + 4]  = av1;
        *(ushort4*)&a_s[lr][lk + 8]  = av2;
        *(ushort4*)&a_s[lr][lk + 12] = av3;
        *(ushort4*)&b_s[lr][lk]      = bv0;
        *(ushort4*)&b_s[lr][lk + 4]  = bv1;
        *(ushort4*)&b_s[lr][lk + 8]  = bv2;
        *(ushort4*)&b_s[lr][lk + 12] = bv3;
        __syncthreads();
        #pragma unroll
        for (int kk = 0; kk < 64; kk += 32) {
            const int kp = kk + g * 8;
            const bf16x8 af = *(const bf16x8*)&a_s[w * 16 + m][kp];
            const bf16x8 b0 = *(const bf16x8*)&b_s[ 0 + m][kp];
            const bf16x8 b1 = *(const bf16x8*)&b_s[16 + m][kp];
            const bf16x8 b2 = *(const bf16x8*)&b_s[32 + m][kp];
            const bf16x8 b3 = *(const bf16x8*)&b_s[48 + m][kp];
            acc[0] = __builtin_amdgcn_mfma_f32_16x16x32_bf16(af, b0, acc[0], 0, 0, 0);
            acc[1] = __builtin_amdgcn_mfma_f32_16x16x32_bf16(af, b1, acc[1], 0, 0, 0);
            acc[2] = __builtin_amdgcn_mfma_f32_16x16x32_bf16(af, b2, acc[2], 0, 0, 0);
            acc[3] = __builtin_amdgcn_mfma_f32_16x16x32_bf16(af, b3, acc[3], 0, 0, 0);
        }
        __syncthreads();
    }

    const int colbase = cOffY * y;
    #pragma unroll
    for (int nt = 0; nt < 4; nt++) {
        const int col = colbase + nt * 16 + m;
        const float bs = bias[col];
        #pragma unroll
        for (int j = 0; j < 4; j++) {
            const int row = m0 + w * 16 + g * 4 + j;
            const float val = acc[nt][j] + bs;
            if (sizeof(CT) == 2) {
                ((unsigned short*)C)[(size_t)row * ldc + col] = f2bf(val);
            } else {
                ((float*)C)[(size_t)row * ldc + col] = val;
            }
        }
    }
}

// ---------------------------------------------------------------------------
extern "C" void kernel_launch(void* const* d_in, const int* in_sizes, int n_in,
                              void* d_out, int out_size, void* d_ws, size_t ws_size,
                              hipStream_t stream)
{
    const float* ents = (const float*)d_in[0];
    const float* qp   = (const float*)d_in[1];
    const float* wq   = (const float*)d_in[2];
    const float* wk   = (const float*)d_in[3];
    const float* wv   = (const float*)d_in[4];
    const float* wo   = (const float*)d_in[5];
    const float* bq   = (const float*)d_in[6];
    // d_in[7] = bk: per-head softmax-invariant constant -> algebraically unused
    const float* bv   = (const float*)d_in[8];
    const float* bo   = (const float*)d_in[9];

    // workspace layout (~44 MB)
    char* ws = (char*)d_ws;
    unsigned short* u_bf     = (unsigned short*)ws;                        // 16 KB [16][512]
    unsigned short* wv_bf    = (unsigned short*)(ws + 65536);              // 512 KB
    unsigned short* wo_bf    = (unsigned short*)(ws + 65536 + 524288);     // 512 KB
    float*          scores   = (float*)(ws + 2097152);                     // 2 MB [sb][h][e]
    float*          p_t      = (float*)(ws + 4194304);                     // 2 MB [sb][e][h]
    unsigned short* weighted = (unsigned short*)(ws + 6291456);            // 32 MB [4096][4096]
    unsigned short* ctx      = (unsigned short*)(ws + 6291456 + 33554432); // 4 MB [4096][512]

    k_prep    <<<528, 256, 0, stream>>>(qp, wq, bq, wk, wv, wo, u_bf, wv_bf, wo_bf);
    k_score   <<<1024, 256, 0, stream>>>(ents, u_bf, scores);
    k_softmax <<<128, 256, 0, stream>>>(scores, p_t);
    k_weighted<<<1024, 256, 0, stream>>>(ents, p_t, weighted);
    k_gemm<unsigned short><<<dim3(64, 8), 256, 0, stream>>>(
        weighted, HEADS * DIM, DIM, wv_bf, DIM, HD, bv, ctx, DIM, HD, DIM);
    k_gemm<float><<<dim3(64, 8), 256, 0, stream>>>(
        ctx, DIM, 0, wo_bf, DIM, HD, bo, (float*)d_out, DIM, HD, DIM);
}

// Round 7
// 65.194 us; speedup vs baseline: 2.1089x; 1.3943x over previous
//
#include <hip/hip_runtime.h>
#include <stdint.h>

// Problem constants (fixed shapes from the reference)
#define HEADS 8
#define DIM   512
#define HD    64
#define NE    16      // entities per sentence
#define NS    64      // sentences
#define NB    64      // batch

typedef short bf16x8 __attribute__((ext_vector_type(8)));
typedef float f32x4  __attribute__((ext_vector_type(4)));

__device__ __forceinline__ unsigned short f2bf(float f) {
    union { float f; uint32_t u; } v; v.f = f;
    uint32_t u = v.u;
    u += 0x7fffu + ((u >> 16) & 1u);   // RNE
    return (unsigned short)(u >> 16);
}
__device__ __forceinline__ float bf_lo(uint32_t u) {
    union { uint32_t u; float f; } v; v.u = u << 16; return v.f;
}
__device__ __forceinline__ float bf_hi(uint32_t u) {
    union { uint32_t u; float f; } v; v.u = u & 0xffff0000u; return v.f;
}

// pack fp32 -> bf16 via HW RNE converts (no builtin on gfx950 -> asm)
__device__ __forceinline__ uint32_t cvt2(float a, float b) {
    uint32_t r;
    asm("v_cvt_pk_bf16_f32 %0, %1, %2" : "=v"(r) : "v"(a), "v"(b));
    return r;
}
__device__ __forceinline__ uint2 cvt4(float4 v) {
    return (uint2){cvt2(v.x, v.y), cvt2(v.z, v.w)};
}
__device__ __forceinline__ uint2 cvt4f(f32x4 v) {
    return (uint2){cvt2(v.x, v.y), cvt2(v.z, v.w)};
}

// ---------------------------------------------------------------------------
// K0: fused prep (528 blocks).
//   blocks [0,16):    u_bf[h][c] = bf16( sum_j qvec_h[j] * wk[h*64+j][c] ),
//                     qvec_h computed in-block; rows 8..15 zeroed.
//   blocks [16,272):  wv -> bf16
//   blocks [272,528): wo -> bf16
// q_h · bk_h is softmax-invariant -> bk unused.
// ---------------------------------------------------------------------------
__global__ __launch_bounds__(256) void k_prep(
    const float* __restrict__ qp, const float* __restrict__ wq,
    const float* __restrict__ bq, const float* __restrict__ wk,
    const float* __restrict__ wv, const float* __restrict__ wo,
    unsigned short* __restrict__ u_bf,
    unsigned short* __restrict__ wv_bf, unsigned short* __restrict__ wo_bf)
{
    const int bid = blockIdx.x;
    const int t = threadIdx.x;
    if (bid < 16) {
        const int h = bid >> 1, ch = bid & 1;
        __shared__ float qs[HD];
        {   // qvec for head h: thread (j = t>>2, q = t&3) sums 128 elems
            const int j = t >> 2, q = t & 3;
            const float* w = wq + (size_t)(h * HD + j) * DIM + q * 128;
            const float* qq = qp + q * 128;
            float a = 0.f;
            #pragma unroll 8
            for (int i = 0; i < 128; i++) a += w[i] * qq[i];
            a += __shfl_xor(a, 1);
            a += __shfl_xor(a, 2);
            if (q == 0) qs[j] = a + bq[h * HD + j];
        }
        __syncthreads();
        const int c = ch * 256 + t;
        const float* w = wk + (size_t)(h * HD) * DIM + c;
        float acc = 0.f;
        #pragma unroll 8
        for (int j = 0; j < HD; j++) acc += qs[j] * w[(size_t)j * DIM];
        u_bf[h * DIM + c] = f2bf(acc);
        u_bf[(h + 8) * DIM + c] = 0;           // zero pad rows for MFMA N=16
        return;
    }
    const bool is_v = bid < 272;
    const float* src = is_v ? wv : wo;
    unsigned short* dst = is_v ? wv_bf : wo_bf;
    const int li = ((is_v ? bid - 16 : bid - 272) * 1024 + t * 4);
    const float4 v = *(const float4*)(src + li);
    ushort4 hv;
    hv.x = f2bf(v.x); hv.y = f2bf(v.y); hv.z = f2bf(v.z); hv.w = f2bf(v.w);
    *(ushort4*)(dst + li) = hv;
}

// ---------------------------------------------------------------------------
// K1: fused score/softmax/weighted-aggregation.
// Block = (s, 2 batch slots): 2048 blocks, 32KB LDS -> 4 blocks/CU, 16 waves/CU.
//   stage:   16 iters: 1 coalesced float4 load + 2 cvt_pk + ds_write_b64.
//            LDS row r = e*2+bb (1KB), byte swizzle ^ (e&7)<<4.
//   score:   waves 0,1 (b = w): one MFMA chain (16 steps) over LDS A-frags +
//            global u_bf B-frags; softmax via 2 shuffles (e=4g+j, h=lane&15).
//   weighted: 4 waves: bb = w&1, d-half = w>>1; lane owns 4 d x 8 heads.
// ---------------------------------------------------------------------------
__global__ __launch_bounds__(256, 4) void k_attn(
    const float* __restrict__ ents, const unsigned short* __restrict__ u_bf,
    unsigned short* __restrict__ weighted)
{
    __shared__ unsigned short ent[2 * NE * DIM];   // 32 KB, swizzled
    __shared__ float attn_s[2][NE][8];             // 1 KB
    const int t = threadIdx.x;
    const int bid = blockIdx.x;
    const int s = bid >> 5;
    const int bg = (bid & 31) << 1;
    const int w = t >> 6, lane = t & 63;

    // ---- stage: iter i = entity e; thread covers float4 d4 = t&127, bb = t>>7 ----
    {
        const int bb = t >> 7, d4 = t & 127;
        const float* p = ents + ((size_t)((s * NE) * NB + bg + bb) << 9) + (d4 << 2);
        const uint32_t dstb = (uint32_t)(t << 3);
        #pragma unroll
        for (int i = 0; i < NE; i++) {
            const float4 v = *(const float4*)(p + (size_t)i * (NB * DIM));
            const uint2 hv = cvt4(v);
            const uint32_t off = ((uint32_t)(i << 11) | dstb) ^ (uint32_t)((i & 7) << 4);
            *(uint2*)((char*)ent + off) = hv;
        }
    }
    __syncthreads();

    // ---- score MFMA + softmax (waves 0,1 handle b = bg + w) ----
    if (w < 2) {
        const int m = lane & 15, g = lane >> 4;
        const uint32_t swz = (uint32_t)((m & 7) << 4);
        const uint32_t rowb = (uint32_t)((m * 2 + w) << 10);
        const unsigned short* urow = u_bf + m * DIM + g * 8;
        f32x4 acc = {0.f, 0.f, 0.f, 0.f};
        #pragma unroll
        for (int ks = 0; ks < 16; ks++) {
            const int kp = g * 8 + ks * 32;
            const bf16x8 af = *(const bf16x8*)((const char*)ent + ((rowb + (uint32_t)(kp << 1)) ^ swz));
            const bf16x8 bf = *(const bf16x8*)(urow + ks * 32);
            acc = __builtin_amdgcn_mfma_f32_16x16x32_bf16(af, bf, acc, 0, 0, 0);
        }
        const float scale = 0.125f;   // 1/sqrt(64)
        float s0 = acc[0]*scale, s1 = acc[1]*scale, s2 = acc[2]*scale, s3 = acc[3]*scale;
        float mx = fmaxf(fmaxf(s0, s1), fmaxf(s2, s3));
        mx = fmaxf(mx, __shfl_xor(mx, 16));
        mx = fmaxf(mx, __shfl_xor(mx, 32));
        const float p0 = __expf(s0 - mx), p1 = __expf(s1 - mx);
        const float p2 = __expf(s2 - mx), p3 = __expf(s3 - mx);
        float sm = p0 + p1 + p2 + p3;
        sm += __shfl_xor(sm, 16);
        sm += __shfl_xor(sm, 32);
        const float inv = 1.f / sm;
        if (m < HEADS) {             // h = m
            attn_s[w][4 * g + 0][m] = p0 * inv;
            attn_s[w][4 * g + 1][m] = p1 * inv;
            attn_s[w][4 * g + 2][m] = p2 * inv;
            attn_s[w][4 * g + 3][m] = p3 * inv;
        }
    }
    __syncthreads();

    // ---- weighted sum: wave w -> (bb = w&1, d-half = w>>1); 4 d per lane ----
    {
        const int bb = w & 1, dh = w >> 1;
        const uint32_t dbyte = (uint32_t)((dh << 9) | (lane << 3));
        f32x4 acc[HEADS];
        #pragma unroll
        for (int h = 0; h < HEADS; h++) acc[h] = (f32x4){0.f, 0.f, 0.f, 0.f};

        #pragma unroll
        for (int e = 0; e < NE; e++) {
            const uint32_t off = ((uint32_t)((e * 2 + bb) << 10) | dbyte) ^ (uint32_t)((e & 7) << 4);
            const uint2 rv = *(const uint2*)((const char*)ent + off);
            const f32x4 ev = {bf_lo(rv.x), bf_hi(rv.x), bf_lo(rv.y), bf_hi(rv.y)};
            const f32x4 a0 = *(const f32x4*)&attn_s[bb][e][0];   // broadcast
            const f32x4 a1 = *(const f32x4*)&attn_s[bb][e][4];
            acc[0] += a0.x * ev; acc[1] += a0.y * ev;
            acc[2] += a0.z * ev; acc[3] += a0.w * ev;
            acc[4] += a1.x * ev; acc[5] += a1.y * ev;
            acc[6] += a1.z * ev; acc[7] += a1.w * ev;
        }
        const int sb = s * NB + bg + bb;
        const int d0 = (dh << 8) | (lane << 2);
        unsigned short* wrow = weighted + ((size_t)sb << 12) + d0;
        #pragma unroll
        for (int h = 0; h < HEADS; h++) {
            *(uint2*)(wrow + h * DIM) = cvt4f(acc[h]);
        }
    }
}

// ---------------------------------------------------------------------------
// K2/K3: C[M=4096, 64 cols per y] = A(bf16) @ B^T(bf16) + bias
// BM=64, BN=64, BK=64; 4 waves, each wave a 16-row strip x 64 cols.
//   K2: A=weighted (lda 4096, col off 512*y=head), B=wv_bf rows 64y.. -> ctx bf16
//   K3: A=ctx      (lda 512),                      B=wo_bf rows 64y.. -> out f32
// ---------------------------------------------------------------------------
template <typename CT>
__global__ __launch_bounds__(256) void k_gemm(
    const unsigned short* __restrict__ A, int lda, int aOffY,
    const unsigned short* __restrict__ B, int ldb, int bOffY,
    const float* __restrict__ bias, CT* __restrict__ C, int ldc, int cOffY, int K)
{
    __shared__ unsigned short a_s[64][72];
    __shared__ unsigned short b_s[64][72];
    const int t = threadIdx.x;
    const int m0 = blockIdx.x * 64;
    const int y  = blockIdx.y;
    const int w = t >> 6, l = t & 63;
    const int m = l & 15, g = l >> 4;
    const int lr = t >> 2, lk = (t & 3) * 16;

    const unsigned short* Ap = A + (size_t)(m0 + lr) * lda + (size_t)aOffY * y;
    const unsigned short* Bp = B + (size_t)(bOffY * y + lr) * ldb;

    f32x4 acc[4];
    #pragma unroll
    for (int i = 0; i < 4; i++) acc[i] = (f32x4){0.f, 0.f, 0.f, 0.f};

    for (int k0 = 0; k0 < K; k0 += 64) {
        const ushort4 av0 = *(const ushort4*)(Ap + k0 + lk);
        const ushort4 av1 = *(const ushort4*)(Ap + k0 + lk + 4);
        const ushort4 av2 = *(const ushort4*)(Ap + k0 + lk + 8);
        const ushort4 av3 = *(const ushort4*)(Ap + k0 + lk + 12);
        const ushort4 bv0 = *(const ushort4*)(Bp + k0 + lk);
        const ushort4 bv1 = *(const ushort4*)(Bp + k0 + lk + 4);
        const ushort4 bv2 = *(const ushort4*)(Bp + k0 + lk + 8);
        const ushort4 bv3 = *(const ushort4*)(Bp + k0 + lk + 12);
        *(ushort4*)&a_s[lr][lk]      = av0;
        *(ushort4*)&a_s[lr][lk + 4]  = av1;
        *(ushort4*)&a_s[lr][lk + 8]  = av2;
        *(ushort4*)&a_s[lr][lk + 12] = av3;
        *(ushort4*)&b_s[lr][lk]      = bv0;
        *(ushort4*)&b_s[lr][lk + 4]  = bv1;
        *(ushort4*)&b_s[lr][lk + 8]  = bv2;
        *(ushort4*)&b_s[lr][lk + 12] = bv3;
        __syncthreads();
        #pragma unroll
        for (int kk = 0; kk < 64; kk += 32) {
            const int kp = kk + g * 8;
            const bf16x8 af = *(const bf16x8*)&a_s[w * 16 + m][kp];
            const bf16x8 b0 = *(const bf16x8*)&b_s[ 0 + m][kp];
            const bf16x8 b1 = *(const bf16x8*)&b_s[16 + m][kp];
            const bf16x8 b2 = *(const bf16x8*)&b_s[32 + m][kp];
            const bf16x8 b3 = *(const bf16x8*)&b_s[48 + m][kp];
            acc[0] = __builtin_amdgcn_mfma_f32_16x16x32_bf16(af, b0, acc[0], 0, 0, 0);
            acc[1] = __builtin_amdgcn_mfma_f32_16x16x32_bf16(af, b1, acc[1], 0, 0, 0);
            acc[2] = __builtin_amdgcn_mfma_f32_16x16x32_bf16(af, b2, acc[2], 0, 0, 0);
            acc[3] = __builtin_amdgcn_mfma_f32_16x16x32_bf16(af, b3, acc[3], 0, 0, 0);
        }
        __syncthreads();
    }

    const int colbase = cOffY * y;
    #pragma unroll
    for (int nt = 0; nt < 4; nt++) {
        const int col = colbase + nt * 16 + m;
        const float bs = bias[col];
        #pragma unroll
        for (int j = 0; j < 4; j++) {
            const int row = m0 + w * 16 + g * 4 + j;
            const float val = acc[nt][j] + bs;
            if (sizeof(CT) == 2) {
                ((unsigned short*)C)[(size_t)row * ldc + col] = f2bf(val);
            } else {
                ((float*)C)[(size_t)row * ldc + col] = val;
            }
        }
    }
}

// ---------------------------------------------------------------------------
extern "C" void kernel_launch(void* const* d_in, const int* in_sizes, int n_in,
                              void* d_out, int out_size, void* d_ws, size_t ws_size,
                              hipStream_t stream)
{
    const float* ents = (const float*)d_in[0];
    const float* qp   = (const float*)d_in[1];
    const float* wq   = (const float*)d_in[2];
    const float* wk   = (const float*)d_in[3];
    const float* wv   = (const float*)d_in[4];
    const float* wo   = (const float*)d_in[5];
    const float* bq   = (const float*)d_in[6];
    // d_in[7] = bk: per-head softmax-invariant constant -> algebraically unused
    const float* bv   = (const float*)d_in[8];
    const float* bo   = (const float*)d_in[9];

    // workspace layout (~40 MB)
    char* ws = (char*)d_ws;
    unsigned short* u_bf     = (unsigned short*)ws;                        // 16 KB [16][512]
    unsigned short* wv_bf    = (unsigned short*)(ws + 65536);              // 512 KB
    unsigned short* wo_bf    = (unsigned short*)(ws + 65536 + 524288);     // 512 KB
    unsigned short* weighted = (unsigned short*)(ws + 2097152);            // 32 MB [4096][4096]
    unsigned short* ctx      = (unsigned short*)(ws + 2097152 + 33554432); // 4 MB [4096][512]

    k_prep <<<528, 256, 0, stream>>>(qp, wq, bq, wk, wv, wo, u_bf, wv_bf, wo_bf);
    k_attn <<<2048, 256, 0, stream>>>(ents, u_bf, weighted);
    k_gemm<unsigned short><<<dim3(64, 8), 256, 0, stream>>>(
        weighted, HEADS * DIM, DIM, wv_bf, DIM, HD, bv, ctx, DIM, HD, DIM);
    k_gemm<float><<<dim3(64, 8), 256, 0, stream>>>(
        ctx, DIM, 0, wo_bf, DIM, HD, bo, (float*)d_out, DIM, HD, DIM);
}